// Round 1
// 224.324 us; speedup vs baseline: 1.1313x; 1.1313x over previous
//
#include <hip/hip_runtime.h>

// ---------------------------------------------------------------------------
// minerva_35124242547419 — R10: kill redundant staging work.
// R9 counters: fused_sim 85us @ MfmaUtil 18 / VALU 17 / HBM 3.2% / occ 22%
//   -> issue+LDS bound, not memory bound. proj re-converts the full f32 W
//   (128 cvts/thread/iter, 640x16 redundant) -> VALU-bound.
// Changes:
//  1. convert_w (one-time): g_w f32 -> bf16 in pre-swizzled per-kslab-linear
//     layout W2. proj stages Ws via 8x global_load_lds (linear addr, 0 cvt,
//     0 ds_write). Ws unpadded [256][64] + XOR(row&7) bank swizzle.
//  2. fused_sim: Ks staged via global_load_lds, swizzle realized on the
//     per-lane GLOBAL source addr (m173 pattern), Ks unpadded [64][256],
//     read XORs the same involution. Removes 8 glb->VGPR + 8 ds_write_b128
//     per thread per t-iter.
// I/O contract (R4-R6): f32 inputs resolved BY SIZE, f32 output.
// ---------------------------------------------------------------------------

typedef __bf16 bf16x8 __attribute__((ext_vector_type(8)));
typedef __bf16 bf16x4 __attribute__((ext_vector_type(4)));
typedef float  f32x4  __attribute__((ext_vector_type(4)));

__device__ __forceinline__ f32x4 f4zero() { f32x4 z = {0.f, 0.f, 0.f, 0.f}; return z; }

__device__ __forceinline__ f32x4 mfma16(bf16x8 a, bf16x8 b, f32x4 c) {
  return __builtin_amdgcn_mfma_f32_16x16x32_bf16(a, b, c, 0, 0, 0);
}

// 8 consecutive f32 -> bf16x8
__device__ __forceinline__ bf16x8 load8f(const float* p) {
  f32x4 a = *(const f32x4*)p;
  f32x4 b = *(const f32x4*)(p + 4);
  bf16x8 r;
  r[0] = (__bf16)a[0]; r[1] = (__bf16)a[1]; r[2] = (__bf16)a[2]; r[3] = (__bf16)a[3];
  r[4] = (__bf16)b[0]; r[5] = (__bf16)b[1]; r[6] = (__bf16)b[2]; r[7] = (__bf16)b[3];
  return r;
}

// async 16B global -> LDS (wave-uniform base + lane*16 dest; per-lane gsrc)
__device__ __forceinline__ void async16(const void* g, void* l) {
  __builtin_amdgcn_global_load_lds(
      (const __attribute__((address_space(1))) unsigned int*)g,
      (__attribute__((address_space(3))) unsigned int*)l, 16, 0, 0);
}

__global__ void zero_f32(float* __restrict__ p, int n) {
  for (int i = blockIdx.x * 256 + threadIdx.x; i < n; i += gridDim.x * 256) p[i] = 0.f;
}

__global__ void fill_sentinel(float* __restrict__ out, int n) {
  for (int i = blockIdx.x * 256 + threadIdx.x; i < n; i += gridDim.x * 256) out[i] = -1.0f;
}

// ---------------------------------------------------------------------------
// One-time W prep: f32 [256][1024] -> bf16, laid out per k-slab (ks 0..15)
// linearly as W2[ks*16384 + (row*8 + c4')*8 + t] = W[row][ks*64 + (c4'^(row&7))*8 + t]
// so proj's global_load_lds addresses are fully linear and the LDS image is
// XOR-swizzled for conflict-free fragment reads.
// ---------------------------------------------------------------------------
__global__ void convert_w(const float* __restrict__ W, __bf16* __restrict__ W2) {
  int i = blockIdx.x * 256 + threadIdx.x;  // 0..32767 (16B chunk id)
  int ks  = i >> 11;
  int idx = i & 2047;
  int row = idx >> 3;
  int c4  = (idx & 7) ^ (row & 7);
  *(bf16x8*)(W2 + (size_t)i * 8) = load8f(W + (size_t)row * 1024 + ks * 64 + c4 * 8);
}

// ---------------------------------------------------------------------------
// P = l2norm_rows(X @ W^T). Block: 32 rows x 256 cols, BK=64, 16 k-iters.
// 4 waves side-by-side in N. Ws now via global_load_lds from pre-swizzled W2.
// blocks 0..511 -> ex_features, 512..639 -> features. LDS ~38 KB.
// ---------------------------------------------------------------------------
__global__ __launch_bounds__(256, 3)
void proj_l2norm(const float* __restrict__ Xa, const float* __restrict__ Xb,
                 const __bf16* __restrict__ W2,
                 __bf16* __restrict__ Pa, __bf16* __restrict__ Pb) {
  __shared__ __align__(16) __bf16 Xs[32 * 72];    // 4.5 KB (padded, cvt path)
  __shared__ __align__(16) __bf16 Ws[256 * 64];   // 32 KB (swizzled, DMA path)
  __shared__ float nrmW[4 * 32];
  __shared__ float invn[32];

  const int tid = threadIdx.x;
  const int w = tid >> 6, lane = tid & 63;
  const int quad = lane >> 4, l15 = lane & 15;
  const int sw = l15 & 7;

  const float* X;
  __bf16* P;
  int row0;
  if (blockIdx.x < 512) { X = Xa; P = Pa; row0 = blockIdx.x * 32; }
  else                  { X = Xb; P = Pb; row0 = (blockIdx.x - 512) * 32; }

  f32x4 acc[2][4];
#pragma unroll
  for (int i = 0; i < 2; i++)
#pragma unroll
    for (int j = 0; j < 4; j++) acc[i][j] = f4zero();

  for (int ks = 0; ks < 16; ks++) {
    __syncthreads();
    // Xs [32][64] (pad 72): 256 bf16x8, 1/thread, f32 src + cvt
    {
      int row = tid >> 3, c8 = tid & 7;
      *(bf16x8*)(Xs + row * 72 + c8 * 8) =
          load8f(X + (size_t)(row0 + row) * 1024 + ks * 64 + c8 * 8);
    }
    // Ws: 2048 chunks via DMA, 8/thread, LINEAR source (swizzle baked in W2)
    {
      const __bf16* w2k = W2 + (size_t)ks * 16384;
#pragma unroll
      for (int rep = 0; rep < 8; rep++) {
        int idx = rep * 256 + tid;
        async16(w2k + idx * 8, Ws + idx * 8);
      }
    }
    __syncthreads();  // drains vmcnt(0): DMA data visible
#pragma unroll
    for (int ksub = 0; ksub < 2; ksub++) {
      bf16x8 af[2], bfr[4];
#pragma unroll
      for (int mb = 0; mb < 2; mb++)
        af[mb] = *(bf16x8*)(Xs + (mb * 16 + l15) * 72 + ksub * 32 + quad * 8);
#pragma unroll
      for (int nb = 0; nb < 4; nb++) {
        int c4 = ksub * 4 + quad;
        bfr[nb] = *(bf16x8*)(Ws + (w * 64 + nb * 16 + l15) * 64 + (c4 ^ sw) * 8);
      }
#pragma unroll
      for (int mb = 0; mb < 2; mb++)
#pragma unroll
        for (int nb = 0; nb < 4; nb++)
          acc[mb][nb] = mfma16(af[mb], bfr[nb], acc[mb][nb]);
    }
  }

  // row sum-of-squares: in-lane over nb, shfl over l15, cross-wave via LDS
  float part[2][4];
#pragma unroll
  for (int mb = 0; mb < 2; mb++)
#pragma unroll
    for (int r = 0; r < 4; r++) {
      float s = 0.f;
#pragma unroll
      for (int nb = 0; nb < 4; nb++) { float v = acc[mb][nb][r]; s += v * v; }
      part[mb][r] = s;
    }
#pragma unroll
  for (int m = 1; m < 16; m <<= 1)
#pragma unroll
    for (int mb = 0; mb < 2; mb++)
#pragma unroll
      for (int r = 0; r < 4; r++) part[mb][r] += __shfl_xor(part[mb][r], m, 64);

  if (l15 == 0) {
#pragma unroll
    for (int mb = 0; mb < 2; mb++)
#pragma unroll
      for (int r = 0; r < 4; r++)
        nrmW[w * 32 + mb * 16 + quad * 4 + r] = part[mb][r];
  }
  __syncthreads();
  if (tid < 32) {
    float s = nrmW[tid] + nrmW[32 + tid] + nrmW[64 + tid] + nrmW[96 + tid];
    invn[tid] = 1.0f / fmaxf(sqrtf(s), 1e-12f);
  }
  __syncthreads();
#pragma unroll
  for (int mb = 0; mb < 2; mb++)
#pragma unroll
    for (int nb = 0; nb < 4; nb++)
#pragma unroll
      for (int r = 0; r < 4; r++) {
        int row = mb * 16 + quad * 4 + r;
        int col = w * 64 + nb * 16 + l15;
        P[(size_t)(row0 + row) * 256 + col] = (__bf16)(acc[mb][nb][r] * invn[row]);
      }
}

// ---------------------------------------------------------------------------
// vT[j][e] = l1norm_row(ex_classes)[e][j] bf16, rows 28..31 zero-padded.
// ---------------------------------------------------------------------------
__global__ void build_vt(const float* __restrict__ exc, __bf16* __restrict__ vT) {
  int e = blockIdx.x * 256 + threadIdx.x;
  float m[28];
  float s = 0.f;
#pragma unroll
  for (int j = 0; j < 28; j++) {
    m[j] = exc[(size_t)e * 28 + j];
    s += fabsf(m[j]);
  }
  float inv = 1.0f / fmaxf(s, 1e-12f);
#pragma unroll
  for (int j = 0; j < 28; j++) vT[(size_t)j * 16384 + e] = (__bf16)(m[j] * inv);
#pragma unroll
  for (int j = 28; j < 32; j++) vT[(size_t)j * 16384 + e] = (__bf16)0.0f;
}

// ---------------------------------------------------------------------------
// Fused flash-style pass. R10: Ks via global_load_lds, unpadded [64][256],
// XOR(row&7) swizzle realized on the per-lane GLOBAL source address;
// read side applies the same involution. Vs/Us unchanged. LDS 54.5 KB.
// ---------------------------------------------------------------------------
__global__ __launch_bounds__(256, 2)
void fused_sim(const __bf16* __restrict__ fn, const __bf16* __restrict__ efn,
               const __bf16* __restrict__ vTg,
               float* __restrict__ tT, float* __restrict__ r_acc) {
  __shared__ __align__(16) __bf16 Ks[64 * 256];   // 32 KB, swizzled
  __shared__ __align__(16) __bf16 Vs[32 * 72];
  __shared__ __align__(16) __bf16 Us[128 * 72];

  const int tid = threadIdx.x, w = tid >> 6, lane = tid & 63;
  const int quad = lane >> 4, l15 = lane & 15;
  const int wy = w >> 1, wx = w & 1;
  const int swk = l15 & 7;
  const int chunk = blockIdx.x & 15, mtile = blockIdx.x >> 4;
  const int q0 = mtile * 128;
  const int e_base = chunk * 1024;

  // per-thread swizzled source offsets for Ks staging (constant across t)
  int koff[8];
#pragma unroll
  for (int rep = 0; rep < 8; rep++) {
    int idx = rep * 256 + tid;     // 0..2047: row = idx>>5, chunk c5' = idx&31
    int row = idx >> 5;
    int c5  = (idx & 31) ^ (row & 7);
    koff[rep] = row * 256 + c5 * 8;  // bf16 elements within the e-tile
  }

  bf16x8 qf[8][4];
#pragma unroll
  for (int ks = 0; ks < 8; ks++)
#pragma unroll
    for (int nb = 0; nb < 4; nb++)
      qf[ks][nb] = *(const bf16x8*)(fn + (size_t)(q0 + wx * 64 + nb * 16 + l15) * 256 +
                                    ks * 32 + quad * 8);

  float r_part[4] = {0.f, 0.f, 0.f, 0.f};
  f32x4 accp[2][2];
#pragma unroll
  for (int a = 0; a < 2; a++)
#pragma unroll
    for (int b = 0; b < 2; b++) accp[a][b] = f4zero();

  for (int t = 0; t < 16; t++) {
    const int e_t = e_base + t * 64;

    __syncthreads();
    // Ks: 2048 chunks via DMA, 8/thread; source pre-swizzled per lane
    {
      const __bf16* src = efn + (size_t)e_t * 256;
#pragma unroll
      for (int rep = 0; rep < 8; rep++)
        async16(src + koff[rep], Ks + (rep * 256 + tid) * 8);
    }
    // Vs: 1 chunk/thread (manual, padded 72)
    {
      int row = tid >> 3, c8 = tid & 7;
      *(bf16x8*)(Vs + row * 72 + c8 * 8) =
          *(const bf16x8*)(vTg + (size_t)row * 16384 + e_t + c8 * 8);
    }
    __syncthreads();  // drains vmcnt(0): Ks DMA visible

    f32x4 accs[2][4];
#pragma unroll
    for (int a = 0; a < 2; a++)
#pragma unroll
      for (int b = 0; b < 4; b++) accs[a][b] = f4zero();
#pragma unroll
    for (int ks = 0; ks < 8; ks++) {
      bf16x8 af[2];
#pragma unroll
      for (int mb = 0; mb < 2; mb++)
        af[mb] = *(bf16x8*)(Ks + (wy * 32 + mb * 16 + l15) * 256 +
                            ((ks * 4 + quad) ^ swk) * 8);
#pragma unroll
      for (int mb = 0; mb < 2; mb++)
#pragma unroll
        for (int nb = 0; nb < 4; nb++)
          accs[mb][nb] = mfma16(af[mb], qf[ks][nb], accs[mb][nb]);
    }

#pragma unroll
    for (int mb = 0; mb < 2; mb++) {
      const int eo = wy * 32 + mb * 16 + quad * 4;
#pragma unroll
      for (int nb = 0; nb < 4; nb++) {
        const int q = wx * 64 + nb * 16 + l15;
        bf16x4 pk;
#pragma unroll
        for (int r = 0; r < 4; r++) {
          float s = accs[mb][nb][r];
          __bf16 ub = (__bf16)(s * s * s);
          pk[r] = ub;
          r_part[nb] += fabsf((float)ub);
        }
        *(bf16x4*)(Us + q * 72 + eo) = pk;
      }
    }
    __syncthreads();

#pragma unroll
    for (int ks = 0; ks < 2; ks++) {
      bf16x8 vf[2], uf[2];
#pragma unroll
      for (int cb = 0; cb < 2; cb++)
        vf[cb] = *(bf16x8*)(Vs + (cb * 16 + l15) * 72 + ks * 32 + quad * 8);
#pragma unroll
      for (int qb = 0; qb < 2; qb++)
        uf[qb] = *(bf16x8*)(Us + (w * 32 + qb * 16 + l15) * 72 + ks * 32 + quad * 8);
#pragma unroll
      for (int cb = 0; cb < 2; cb++)
#pragma unroll
        for (int qb = 0; qb < 2; qb++)
          accp[cb][qb] = mfma16(vf[cb], uf[qb], accp[cb][qb]);
    }
  }

#pragma unroll
  for (int nb = 0; nb < 4; nb++) {
    float v = r_part[nb];
    v += __shfl_xor(v, 16, 64);
    v += __shfl_xor(v, 32, 64);
    if (quad == 0) atomicAdd(&r_acc[q0 + wx * 64 + nb * 16 + l15], v);
  }
#pragma unroll
  for (int cb = 0; cb < 2; cb++)
#pragma unroll
    for (int qb = 0; qb < 2; qb++)
#pragma unroll
      for (int r = 0; r < 4; r++)
        atomicAdd(&tT[(size_t)(cb * 16 + quad * 4 + r) * 4096 + q0 + w * 32 + qb * 16 + l15],
                  accp[cb][qb][r]);
}

// ---------------------------------------------------------------------------
// finalize: WAVE-PER-QUERY (unchanged from R9).
// ---------------------------------------------------------------------------
__global__ __launch_bounds__(256, 4)
void finalize(const float* __restrict__ tT, const float* __restrict__ r_acc,
              const float* __restrict__ creps, const float* __restrict__ labels,
              float* __restrict__ loss_acc, float* __restrict__ out) {
  __shared__ __align__(16) float cr[28 * 64];
  __shared__ float wsum[4];
  const int tid = threadIdx.x, w = tid >> 6, lane = tid & 63;
  for (int i = tid; i < 28 * 64; i += 256) cr[i] = creps[i];
  __syncthreads();

  const int q = blockIdx.x * 4 + w;
  float tval = 0.f;
  if (lane < 28) tval = tT[(size_t)lane * 4096 + q];
  tval *= 1.0f / fmaxf(r_acc[q], 1e-12f);

  // echo[c] for c = lane
  float echo = 0.f;
#pragma unroll
  for (int j = 0; j < 28; j++)
    echo = fmaf(__shfl(tval, j, 64), cr[j * 64 + lane], echo);

  float dj = 0.f;
#pragma unroll
  for (int j = 0; j < 28; j++) {
    float df = echo - cr[j * 64 + lane];
    float d2 = df * df;
#pragma unroll
    for (int m = 1; m < 64; m <<= 1) d2 += __shfl_xor(d2, m, 64);
    if (lane == j) dj = sqrtf(d2);
  }

  float lsum = 0.f;
  if (lane < 28) {
    out[1 + (size_t)q * 28 + lane] = -dj;
    float y = labels[(size_t)q * 28 + lane];
    lsum = fmaf(y, dj, log1pf(expf(-dj)));  // BCEWithLogits(-d, y), d >= 0
  }
#pragma unroll
  for (int m = 1; m < 64; m <<= 1) lsum += __shfl_xor(lsum, m, 64);
  if (lane == 0) wsum[w] = lsum;
  __syncthreads();
  if (tid == 0) atomicAdd(loss_acc, wsum[0] + wsum[1] + wsum[2] + wsum[3]);
}

__global__ void write_loss(const float* __restrict__ loss_acc, float* __restrict__ out) {
  out[0] = loss_acc[0] * (1.0f / 114688.0f);
}

// ---------------------------------------------------------------------------
extern "C" void kernel_launch(void* const* d_in, const int* in_sizes, int n_in,
                              void* d_out, int out_size, void* d_ws, size_t ws_size,
                              hipStream_t stream) {
  // Resolve inputs BY ELEMENT COUNT (unique per input; permutation-proof).
  const float* features = nullptr;  // 4096*1024   = 4194304
  const float* labels   = nullptr;  // 4096*28     = 114688
  const float* ex_feat  = nullptr;  // 16384*1024  = 16777216
  const float* ex_cls   = nullptr;  // 16384*28    = 458752
  const float* g_w      = nullptr;  // 256*1024    = 262144
  const float* creps    = nullptr;  // 28*64       = 1792
  for (int i = 0; i < n_in; i++) {
    switch (in_sizes[i]) {
      case 4194304:  features = (const float*)d_in[i]; break;
      case 114688:   labels   = (const float*)d_in[i]; break;
      case 16777216: ex_feat  = (const float*)d_in[i]; break;
      case 458752:   ex_cls   = (const float*)d_in[i]; break;
      case 262144:   g_w      = (const float*)d_in[i]; break;
      case 1792:     creps    = (const float*)d_in[i]; break;
      default: break;
    }
  }
  float* out = (float*)d_out;  // f32: [loss(1)] ++ [neg_dists 4096*28]

  if (!features || !labels || !ex_feat || !ex_cls || !g_w || !creps ||
      ws_size < (16ull << 20)) {
    fill_sentinel<<<256, 256, 0, stream>>>(out, out_size);  // diagnostic
    return;
  }

  char* ws = (char*)d_ws;
  __bf16* f_n   = (__bf16*)(ws);                    // 2 MB   [4096][256]
  __bf16* ef_n  = (__bf16*)(ws + (2ull << 20));     // 8 MB   [16384][256]
  __bf16* vT    = (__bf16*)(ws + (10ull << 20));    // 1 MB   [32][16384]
  float*  tT    = (float*) (ws + (11ull << 20));    // 512 KB [32][4096]
  float*  r_acc = tT + 32 * 4096;                   // 16 KB
  float*  lossp = r_acc + 4096;                     // 4 B
  __bf16* W2    = (__bf16*)(ws + (12ull << 20));    // 512 KB pre-swizzled bf16 W

  zero_f32<<<528, 256, 0, stream>>>(tT, 32 * 4096 + 4096 + 1);
  convert_w<<<128, 256, 0, stream>>>(g_w, W2);

  proj_l2norm<<<640, 256, 0, stream>>>(ex_feat, features, W2, ef_n, f_n);
  build_vt<<<64, 256, 0, stream>>>(ex_cls, vT);
  fused_sim<<<512, 256, 0, stream>>>(f_n, ef_n, vT, tT, r_acc);
  finalize<<<1024, 256, 0, stream>>>(tT, r_acc, creps, labels, lossp, out);
  write_loss<<<1, 1, 0, stream>>>(lossp, out);
}